// Round 5
// baseline (707787.256 us; speedup 1.0000x reference)
//
#include <hip/hip_runtime.h>
#include <math.h>

#define N_NODES 4096
#define WORDS   64
#define HID     256
#define VOCAB   50257
#define NCLASS  4
#define N_LEAF  2048
#define RNN_BLOCKS 256   // 1 block/CU (16 waves) -> all resident, spin-wait safe
#define FLAG_STRIDE 16   // one 64B line per flag

typedef _Float16 half2_t __attribute__((ext_vector_type(2)));

__device__ __forceinline__ float dot2f(half2_t a, half2_t b, float c) {
#if __has_builtin(__builtin_amdgcn_fdot2)
  return __builtin_amdgcn_fdot2(a, b, c, false);   // v_dot2_f32_f16
#else
  return c + (float)a.x * (float)b.x + (float)a.y * (float)b.y;
#endif
}

// ---------------------------------------------------------------- init flags
__global__ void init_flags_kernel(int* __restrict__ flags) {
  int i = blockIdx.x * blockDim.x + threadIdx.x;
  if (i < N_NODES * FLAG_STRIDE) flags[i] = 0;
}

// ---------------------------------------------------------------- transpose (R,C) -> (C,R); for E only
__global__ void transpose_kernel(const float* __restrict__ src, float* __restrict__ dst,
                                 int R, int C) {
  __shared__ float tile[32][33];
  int c0 = blockIdx.x * 32, r0 = blockIdx.y * 32;
  int tx = threadIdx.x, ty = threadIdx.y;
#pragma unroll
  for (int j = 0; j < 32; j += 8) {
    int c = c0 + tx, r = r0 + ty + j;
    if (c < C) tile[ty + j][tx] = src[(size_t)r * C + c];
  }
  __syncthreads();
#pragma unroll
  for (int j = 0; j < 32; j += 8) {
    int c = c0 + ty + j, r = r0 + tx;
    if (c < C) dst[(size_t)c * R + r] = tile[tx][ty + j];
  }
}

// ---------------------------------------------------------------- pack U -> half2, layout Upk[(m*4+ks)*8192 + j*256 + h]
// pair (k = ks*64+2j, ks*64+2j+1) of U_m[h][k]
__global__ void __launch_bounds__(256) pack_u_kernel(
    const float* __restrict__ Uz, const float* __restrict__ Ur, const float* __restrict__ Uh,
    half2_t* __restrict__ Upk) {
  __shared__ float tile[64][259];
  int m = blockIdx.x >> 2, g = blockIdx.x & 3;
  const float* U = m == 0 ? Uz : (m == 1 ? Ur : Uh);
  int t = threadIdx.x;
  for (int r = 0; r < 64; ++r) tile[r][t] = U[(size_t)(g * 64 + r) * 256 + t];
  __syncthreads();
#pragma unroll
  for (int it = 0; it < 32; ++it) {
    int e = it * 256 + t;
    int hl = e & 63, kj = e >> 6, ks = kj >> 5, j = kj & 31;
    half2_t v;
    v.x = (_Float16)tile[hl][ks * 64 + 2 * j];
    v.y = (_Float16)tile[hl][ks * 64 + 2 * j + 1];
    Upk[(size_t)(m * 4 + ks) * 8192 + j * 256 + (g * 64 + hl)] = v;
  }
}

// ---------------------------------------------------------------- X[i,h] = sum_w E_T[tree[i,w], h]
__global__ void gather_x_kernel(const int* __restrict__ tree, const float* __restrict__ ET,
                                float* __restrict__ X, float* __restrict__ H) {
  int i = blockIdx.x;
  int h = threadIdx.x;
  __shared__ int vs[WORDS];
  if (h < WORDS) vs[h] = tree[i * WORDS + h];
  __syncthreads();
  float acc = 0.f;
#pragma unroll 8
  for (int w = 0; w < WORDS; ++w) acc += ET[(size_t)vs[w] * HID + h];
  X[i * HID + h] = acc;
  if (i == 0) H[h] = acc;   // node 0: h = X[0]
}

// ---------------------------------------------------------------- A = X @ W^T for 3 weights
__global__ void __launch_bounds__(256) gemm3_kernel(
    const float* __restrict__ X,
    const float* __restrict__ W0, const float* __restrict__ W1, const float* __restrict__ W2,
    float* __restrict__ A0, float* __restrict__ A1, float* __restrict__ A2) {
  const float* W = blockIdx.z == 0 ? W0 : (blockIdx.z == 1 ? W1 : W2);
  float*       A = blockIdx.z == 0 ? A0 : (blockIdx.z == 1 ? A1 : A2);
  __shared__ float Xs[16][65];
  __shared__ float Ws[16][65];
  int tid = threadIdx.x;
  int m0 = blockIdx.x * 64, n0 = blockIdx.y * 64;
  int tm = (tid / 16) * 4, tn = (tid % 16) * 4;
  int lm = tid >> 2, lk = (tid & 3) * 4;
  float acc[4][4];
#pragma unroll
  for (int a = 0; a < 4; ++a)
#pragma unroll
    for (int b = 0; b < 4; ++b) acc[a][b] = 0.f;

  for (int k0 = 0; k0 < HID; k0 += 16) {
    float4 xv = *(const float4*)(X + (size_t)(m0 + lm) * HID + k0 + lk);
    Xs[lk + 0][lm] = xv.x; Xs[lk + 1][lm] = xv.y; Xs[lk + 2][lm] = xv.z; Xs[lk + 3][lm] = xv.w;
    float4 wv = *(const float4*)(W + (size_t)(n0 + lm) * HID + k0 + lk);
    Ws[lk + 0][lm] = wv.x; Ws[lk + 1][lm] = wv.y; Ws[lk + 2][lm] = wv.z; Ws[lk + 3][lm] = wv.w;
    __syncthreads();
#pragma unroll
    for (int k = 0; k < 16; ++k) {
      float xm[4], wn[4];
#pragma unroll
      for (int u = 0; u < 4; ++u) { xm[u] = Xs[k][tm + u]; wn[u] = Ws[k][tn + u]; }
#pragma unroll
      for (int a = 0; a < 4; ++a)
#pragma unroll
        for (int b = 0; b < 4; ++b) acc[a][b] = fmaf(xm[a], wn[b], acc[a][b]);
    }
    __syncthreads();
  }
#pragma unroll
  for (int a = 0; a < 4; ++a)
#pragma unroll
    for (int b = 0; b < 4; ++b)
      A[(size_t)(m0 + tm + a) * HID + n0 + tn + b] = acc[a][b];
}

// ---------------------------------------------------------------- persistent wavefront GRU scan, U pinned in registers
// thread (h = tid&255, ks = tid>>8) holds Uz/Ur/Uh[h][ks*64 .. +63] as 3x32 half2 VGPRs.
// R4 post-mortem: __launch_bounds__(1024,4) left the allocator a waves-per-eu range with max 8
// -> 64-VGPR cap -> all 96 pinned U regs spilled to scratch (global-backed) -> unchanged time.
// amdgpu_waves_per_eu(4,4) pins occupancy to exactly 4 waves/EU -> 128-VGPR cap -> no spill.
__global__ void
__attribute__((amdgpu_flat_work_group_size(1024, 1024), amdgpu_waves_per_eu(4, 4)))
rnn_kernel(
    const float* __restrict__ Az, const float* __restrict__ Ar, const float* __restrict__ Ah,
    const half2_t* __restrict__ Upk,
    const float* __restrict__ bz, const float* __restrict__ br, const float* __restrict__ bh,
    const int* __restrict__ edge, float* __restrict__ H, int* flags) {
  const int tid = threadIdx.x;
  const int h   = tid & (HID - 1);
  const int ks  = tid >> 8;        // 0..3
  __shared__ half2_t php[HID / 2];
  __shared__ half2_t rhp[HID / 2];
  __shared__ float part_a[4 * HID];
  __shared__ float part_b[4 * HID];

  half2_t uz[32], ur[32], uh[32];
  {
    const half2_t* bp = Upk + (size_t)ks * 8192 + h;
#pragma unroll
    for (int j = 0; j < 32; ++j) {
      uz[j] = bp[j * 256];
      ur[j] = bp[32768 + j * 256];
      uh[j] = bp[65536 + j * 256];
    }
  }
#pragma unroll
  for (int j = 0; j < 32; ++j) {
    asm volatile("" : "+v"(uz[j]));
    asm volatile("" : "+v"(ur[j]));
    asm volatile("" : "+v"(uh[j]));
  }
  float bzr = 0.f, brr = 0.f, bhr = 0.f;
  if (ks == 0) { bzr = bz[h]; brr = br[h]; bhr = bh[h]; }

  for (int i = blockIdx.x; i < N_NODES; i += RNN_BLOCKS) {
    if (i == 0) {
      if (tid == 0)
        __hip_atomic_store(&flags[0], 1, __ATOMIC_RELAXED, __HIP_MEMORY_SCOPE_AGENT);
      continue;
    }
    const int p = edge[2 * i];   // parent, p < i
    float az = 0.f, ar = 0.f, ah = 0.f;
    if (ks == 0) {               // issue before the wait; completes during spin
      az = Az[(size_t)i * HID + h];
      ar = Ar[(size_t)i * HID + h];
      ah = Ah[(size_t)i * HID + h];
    }
    if (tid == 0) {
      long spin = 0;
      while (__hip_atomic_load(&flags[(size_t)p * FLAG_STRIDE], __ATOMIC_RELAXED,
                               __HIP_MEMORY_SCOPE_AGENT) == 0) {
        if (++spin > (1L << 25)) break;   // escape hatch (should never trigger)
      }
    }
    __syncthreads();

    float phv = 0.f;
    if (ks == 0) {
      phv = __hip_atomic_load(&H[(size_t)p * HID + h], __ATOMIC_RELAXED,
                              __HIP_MEMORY_SCOPE_AGENT);
      float nb = __shfl_xor(phv, 1, 64);
      if ((h & 1) == 0) {
        half2_t v; v.x = (_Float16)phv; v.y = (_Float16)nb;
        php[h >> 1] = v;
      }
    }
    __syncthreads();

    // phase 1: z,r partial dots over this thread's k-slice (registers only)
    float zacc = 0.f, racc = 0.f;
#pragma unroll 8
    for (int j = 0; j < 32; ++j) {
      half2_t ph2 = php[(ks << 5) + j];   // wave-broadcast LDS read
      zacc = dot2f(uz[j], ph2, zacc);
      racc = dot2f(ur[j], ph2, racc);
    }
    part_a[ks * HID + h] = zacc;
    part_b[ks * HID + h] = racc;
    __syncthreads();

    float z = 0.f;
    if (ks == 0) {
      float za = az + bzr + part_a[h] + part_a[HID + h] + part_a[2 * HID + h] + part_a[3 * HID + h];
      float ra = ar + brr + part_b[h] + part_b[HID + h] + part_b[2 * HID + h] + part_b[3 * HID + h];
      z = 1.f / (1.f + expf(-za));
      float r = 1.f / (1.f + expf(-ra));
      float rh = r * phv;
      float nb = __shfl_xor(rh, 1, 64);
      if ((h & 1) == 0) {
        half2_t v; v.x = (_Float16)rh; v.y = (_Float16)nb;
        rhp[h >> 1] = v;
      }
    }
    __syncthreads();

    // phase 2: c partial dots
    float cacc = 0.f;
#pragma unroll 8
    for (int j = 0; j < 32; ++j)
      cacc = dot2f(uh[j], rhp[(ks << 5) + j], cacc);
    part_a[ks * HID + h] = cacc;
    __syncthreads();

    if (ks == 0) {
      float ca = ah + bhr + part_a[h] + part_a[HID + h] + part_a[2 * HID + h] + part_a[3 * HID + h];
      float c  = tanhf(ca);
      float hn = fmaf(z, phv, (1.f - z) * c);
      __hip_atomic_store(&H[(size_t)i * HID + h], hn, __ATOMIC_RELAXED,
                         __HIP_MEMORY_SCOPE_AGENT);
    }
    __builtin_amdgcn_s_waitcnt(0);   // drain this wave's store acks
    __syncthreads();                  // all waves past their waitcnt
    if (tid == 0)
      __hip_atomic_store(&flags[(size_t)i * FLAG_STRIDE], 1, __ATOMIC_RELAXED,
                         __HIP_MEMORY_SCOPE_AGENT);
  }
}

// ---------------------------------------------------------------- leaf max partial (64 blocks x 32 leaves)
__global__ void leafmax_kernel(const float* __restrict__ H, const int* __restrict__ leafs,
                               float* __restrict__ partial) {
  int b = blockIdx.x;
  int h = threadIdx.x;
  float m = -INFINITY;
#pragma unroll 4
  for (int j = 0; j < N_LEAF / 64; ++j) {
    int node = leafs[b * (N_LEAF / 64) + j];
    m = fmaxf(m, H[(size_t)node * HID + h]);
  }
  partial[b * HID + h] = m;
}

// ---------------------------------------------------------------- final: reduce partials, W_out, softmax, loss
__global__ void final_kernel(const float* __restrict__ partial, const float* __restrict__ W_out,
                             const float* __restrict__ b_out, const float* __restrict__ y,
                             float* __restrict__ out) {
  int h = threadIdx.x;
  float m = -INFINITY;
#pragma unroll 8
  for (int b = 0; b < 64; ++b) m = fmaxf(m, partial[b * HID + h]);
  __shared__ float fs[HID];
  __shared__ float red[HID];
  __shared__ float logit[NCLASS];
  fs[h] = m;
  __syncthreads();
  for (int c = 0; c < NCLASS; ++c) {
    red[h] = W_out[c * HID + h] * fs[h];
    __syncthreads();
    for (int s = HID / 2; s > 0; s >>= 1) {
      if (h < s) red[h] += red[h + s];
      __syncthreads();
    }
    if (h == 0) logit[c] = red[0] + b_out[c];
    __syncthreads();
  }
  if (h == 0) {
    float mx = logit[0];
    for (int c = 1; c < NCLASS; ++c) mx = fmaxf(mx, logit[c]);
    float e[NCLASS], s = 0.f;
    for (int c = 0; c < NCLASS; ++c) { e[c] = expf(logit[c] - mx); s += e[c]; }
    float loss = 0.f;
    for (int c = 0; c < NCLASS; ++c) {
      float p = e[c] / s;
      out[c] = p;
      float d = y[c] - p;
      loss += d * d;
    }
    out[NCLASS] = loss;
  }
}

// ---------------------------------------------------------------- launch
extern "C" void kernel_launch(void* const* d_in, const int* in_sizes, int n_in,
                              void* d_out, int out_size, void* d_ws, size_t ws_size,
                              hipStream_t stream) {
  const int*   tree = (const int*)d_in[0];
  const int*   edge = (const int*)d_in[1];
  const int*   leaf = (const int*)d_in[2];
  const float* y    = (const float*)d_in[3];
  const float* E    = (const float*)d_in[4];
  const float* Wz   = (const float*)d_in[5];
  const float* Uz   = (const float*)d_in[6];
  const float* bz   = (const float*)d_in[7];
  const float* Wr   = (const float*)d_in[8];
  const float* Ur   = (const float*)d_in[9];
  const float* br   = (const float*)d_in[10];
  const float* Wh   = (const float*)d_in[11];
  const float* Uh   = (const float*)d_in[12];
  const float* bh   = (const float*)d_in[13];
  const float* Wout = (const float*)d_in[14];
  const float* bout = (const float*)d_in[15];
  float* out = (float*)d_out;

  float* ws = (float*)d_ws;
  size_t off = 0;
  float*   ET  = ws + off; off += (size_t)VOCAB * HID;
  half2_t* Upk = (half2_t*)(ws + off); off += 3 * 4 * 8192;   // 98304 half2 = 49152 floats
  float* X   = ws + off; off += (size_t)N_NODES * HID;
  float* Az  = ws + off; off += (size_t)N_NODES * HID;
  float* Ar  = ws + off; off += (size_t)N_NODES * HID;
  float* Ah  = ws + off; off += (size_t)N_NODES * HID;
  float* H   = ws + off; off += (size_t)N_NODES * HID;
  float* partial = ws + off; off += 64 * HID;
  int*   flags   = (int*)(ws + off); off += N_NODES * FLAG_STRIDE;

  init_flags_kernel<<<(N_NODES * FLAG_STRIDE + 255) / 256, 256, 0, stream>>>(flags);
  transpose_kernel<<<dim3((VOCAB + 31) / 32, HID / 32), dim3(32, 8), 0, stream>>>(E, ET, HID, VOCAB);
  pack_u_kernel<<<12, 256, 0, stream>>>(Uz, Ur, Uh, Upk);
  gather_x_kernel<<<N_NODES, HID, 0, stream>>>(tree, ET, X, H);
  gemm3_kernel<<<dim3(N_NODES / 64, HID / 64, 3), 256, 0, stream>>>(X, Wz, Wr, Wh, Az, Ar, Ah);
  rnn_kernel<<<RNN_BLOCKS, 1024, 0, stream>>>(Az, Ar, Ah, Upk, bz, br, bh, edge, H, flags);
  leafmax_kernel<<<64, HID, 0, stream>>>(H, leaf, partial);
  final_kernel<<<1, HID, 0, stream>>>(partial, Wout, bout, y, out);
}

// Round 6
// 1909.304 us; speedup vs baseline: 370.7043x; 370.7043x over previous
//
#include <hip/hip_runtime.h>
#include <math.h>

#define N_NODES 4096
#define WORDS   64
#define HID     256
#define VOCAB   50257
#define NCLASS  4
#define N_LEAF  2048
#define RNN_BLOCKS 256   // 1 block/CU -> all resident, spin-wait safe
#define FLAG_STRIDE 16   // one 64B line per flag

typedef _Float16 half2_t __attribute__((ext_vector_type(2)));

__device__ __forceinline__ float dot2f(half2_t a, half2_t b, float c) {
#if __has_builtin(__builtin_amdgcn_fdot2)
  return __builtin_amdgcn_fdot2(a, b, c, false);   // v_dot2_f32_f16
#else
  return c + (float)a.x * (float)b.x + (float)a.y * (float)b.y;
#endif
}

// ---------------------------------------------------------------- init flags
__global__ void init_flags_kernel(int* __restrict__ flags) {
  int i = blockIdx.x * blockDim.x + threadIdx.x;
  if (i < N_NODES * FLAG_STRIDE) flags[i] = 0;
}

// ---------------------------------------------------------------- transpose (R,C) -> (C,R); for E only
__global__ void transpose_kernel(const float* __restrict__ src, float* __restrict__ dst,
                                 int R, int C) {
  __shared__ float tile[32][33];
  int c0 = blockIdx.x * 32, r0 = blockIdx.y * 32;
  int tx = threadIdx.x, ty = threadIdx.y;
#pragma unroll
  for (int j = 0; j < 32; j += 8) {
    int c = c0 + tx, r = r0 + ty + j;
    if (c < C) tile[ty + j][tx] = src[(size_t)r * C + c];
  }
  __syncthreads();
#pragma unroll
  for (int j = 0; j < 32; j += 8) {
    int c = c0 + ty + j, r = r0 + tx;
    if (c < C) dst[(size_t)c * R + r] = tile[tx][ty + j];
  }
}

// ---------------------------------------------------------------- pack U -> half2, layout Upk[(m*4+ks4)*8192 + j*256 + h]
// pair (k = ks4*64+2j, ks4*64+2j+1) of U_m[h][k]
__global__ void __launch_bounds__(256) pack_u_kernel(
    const float* __restrict__ Uz, const float* __restrict__ Ur, const float* __restrict__ Uh,
    half2_t* __restrict__ Upk) {
  __shared__ float tile[64][259];
  int m = blockIdx.x >> 2, g = blockIdx.x & 3;
  const float* U = m == 0 ? Uz : (m == 1 ? Ur : Uh);
  int t = threadIdx.x;
  for (int r = 0; r < 64; ++r) tile[r][t] = U[(size_t)(g * 64 + r) * 256 + t];
  __syncthreads();
#pragma unroll
  for (int it = 0; it < 32; ++it) {
    int e = it * 256 + t;
    int hl = e & 63, kj = e >> 6, ks = kj >> 5, j = kj & 31;
    half2_t v;
    v.x = (_Float16)tile[hl][ks * 64 + 2 * j];
    v.y = (_Float16)tile[hl][ks * 64 + 2 * j + 1];
    Upk[(size_t)(m * 4 + ks) * 8192 + j * 256 + (g * 64 + hl)] = v;
  }
}

// ---------------------------------------------------------------- X[i,h] = sum_w E_T[tree[i,w], h]
__global__ void gather_x_kernel(const int* __restrict__ tree, const float* __restrict__ ET,
                                float* __restrict__ X, float* __restrict__ H,
                                half2_t* __restrict__ Hpk) {
  int i = blockIdx.x;
  int h = threadIdx.x;
  __shared__ int vs[WORDS];
  if (h < WORDS) vs[h] = tree[i * WORDS + h];
  __syncthreads();
  float acc = 0.f;
#pragma unroll 8
  for (int w = 0; w < WORDS; ++w) acc += ET[(size_t)vs[w] * HID + h];
  X[i * HID + h] = acc;
  if (i == 0) {
    H[h] = acc;   // node 0 seed (fp32)
    float nb = __shfl_xor(acc, 1, 64);
    if ((h & 1) == 0) {
      half2_t v; v.x = (_Float16)acc; v.y = (_Float16)nb;
      Hpk[h >> 1] = v;   // node 0 seed (packed fp16)
    }
  }
}

// ---------------------------------------------------------------- A = X @ W^T for 3 weights
__global__ void __launch_bounds__(256) gemm3_kernel(
    const float* __restrict__ X,
    const float* __restrict__ W0, const float* __restrict__ W1, const float* __restrict__ W2,
    float* __restrict__ A0, float* __restrict__ A1, float* __restrict__ A2) {
  const float* W = blockIdx.z == 0 ? W0 : (blockIdx.z == 1 ? W1 : W2);
  float*       A = blockIdx.z == 0 ? A0 : (blockIdx.z == 1 ? A1 : A2);
  __shared__ float Xs[16][65];
  __shared__ float Ws[16][65];
  int tid = threadIdx.x;
  int m0 = blockIdx.x * 64, n0 = blockIdx.y * 64;
  int tm = (tid / 16) * 4, tn = (tid % 16) * 4;
  int lm = tid >> 2, lk = (tid & 3) * 4;
  float acc[4][4];
#pragma unroll
  for (int a = 0; a < 4; ++a)
#pragma unroll
    for (int b = 0; b < 4; ++b) acc[a][b] = 0.f;

  for (int k0 = 0; k0 < HID; k0 += 16) {
    float4 xv = *(const float4*)(X + (size_t)(m0 + lm) * HID + k0 + lk);
    Xs[lk + 0][lm] = xv.x; Xs[lk + 1][lm] = xv.y; Xs[lk + 2][lm] = xv.z; Xs[lk + 3][lm] = xv.w;
    float4 wv = *(const float4*)(W + (size_t)(n0 + lm) * HID + k0 + lk);
    Ws[lk + 0][lm] = wv.x; Ws[lk + 1][lm] = wv.y; Ws[lk + 2][lm] = wv.z; Ws[lk + 3][lm] = wv.w;
    __syncthreads();
#pragma unroll
    for (int k = 0; k < 16; ++k) {
      float xm[4], wn[4];
#pragma unroll
      for (int u = 0; u < 4; ++u) { xm[u] = Xs[k][tm + u]; wn[u] = Ws[k][tn + u]; }
#pragma unroll
      for (int a = 0; a < 4; ++a)
#pragma unroll
        for (int b = 0; b < 4; ++b) acc[a][b] = fmaf(xm[a], wn[b], acc[a][b]);
    }
    __syncthreads();
  }
#pragma unroll
  for (int a = 0; a < 4; ++a)
#pragma unroll
    for (int b = 0; b < 4; ++b)
      A[(size_t)(m0 + tm + a) * HID + n0 + tn + b] = acc[a][b];
}

// ---------------------------------------------------------------- persistent wavefront GRU scan, U pinned in registers
// R5 post-mortem: 1024-thread blocks (16 waves = 4 waves/EU minimum) hard-cap the VGPR budget
// at 128/thread; demand was 96 U + ~35 work = 131 > 128 -> allocator forced remat (R3/R4, L2
// streaming) or scratch spill (R5, 227 GB HBM). Fix: 512-thread blocks (8 waves = 2 waves/EU,
// pinned) -> 256-VGPR budget. Thread (h = tid&255, ks = tid>>8 in {0,1}) holds a 128-wide
// k-slice of Uz/Ur/Uh as 3x64 half2 = 192 VGPRs + ~35 working = fits, no spill.
__global__ void
__attribute__((amdgpu_flat_work_group_size(512, 512), amdgpu_waves_per_eu(2, 2)))
rnn_kernel(
    const float* __restrict__ Az, const float* __restrict__ Ar, const float* __restrict__ Ah,
    const half2_t* __restrict__ Upk,
    const float* __restrict__ bz, const float* __restrict__ br, const float* __restrict__ bh,
    const int* __restrict__ edge, float* __restrict__ H, half2_t* __restrict__ Hpk,
    int* flags) {
  const int tid = threadIdx.x;
  const int h   = tid & (HID - 1);
  const int ks  = tid >> 8;        // 0..1
  __shared__ half2_t php[HID / 2];
  __shared__ half2_t rhp[HID / 2];
  __shared__ float part_a[2 * HID];
  __shared__ float part_b[2 * HID];

  // one-time U load into registers: 64 half2 per matrix, k-slice [ks*128, ks*128+128)
  half2_t uz[64], ur[64], uh[64];
  {
    const half2_t* bp = Upk + (size_t)(2 * ks) * 8192 + h;
#pragma unroll
    for (int j = 0; j < 64; ++j) {
      int s = (j >> 5) * 8192 + (j & 31) * 256;
      uz[j] = bp[s];
      ur[j] = bp[32768 + s];
      uh[j] = bp[65536 + s];
    }
  }
#pragma unroll
  for (int j = 0; j < 64; ++j) {
    asm volatile("" : "+v"(uz[j]));
    asm volatile("" : "+v"(ur[j]));
    asm volatile("" : "+v"(uh[j]));
  }
  float bzr = 0.f, brr = 0.f, bhr = 0.f;
  if (ks == 0) { bzr = bz[h]; brr = br[h]; bhr = bh[h]; }

  for (int i = blockIdx.x; i < N_NODES; i += RNN_BLOCKS) {
    if (i == 0) {
      if (tid == 0)
        __hip_atomic_store(&flags[0], 1, __ATOMIC_RELAXED, __HIP_MEMORY_SCOPE_AGENT);
      continue;
    }
    const int p = edge[2 * i];   // parent, p < i
    float az = 0.f, ar = 0.f, ah = 0.f;
    if (ks == 0) {               // issue before the wait; completes during spin
      az = Az[(size_t)i * HID + h];
      ar = Ar[(size_t)i * HID + h];
      ah = Ah[(size_t)i * HID + h];
    }
    if (tid == 0) {
      long spin = 0;
      while (__hip_atomic_load(&flags[(size_t)p * FLAG_STRIDE], __ATOMIC_RELAXED,
                               __HIP_MEMORY_SCOPE_AGENT) == 0) {
        if (++spin > (1L << 25)) break;   // escape hatch (should never trigger)
      }
    }
    __syncthreads();

    // packed parent row (512 B) feeds the dots; fp32 row overlaps with phase-1 compute
    if (tid < HID / 2)
      php[tid] = __hip_atomic_load((const unsigned*)&Hpk[(size_t)p * (HID / 2) + tid],
                                   __ATOMIC_RELAXED, __HIP_MEMORY_SCOPE_AGENT)
                     ? php[tid] : php[tid],   // placeholder never taken (see below)
      php[tid] = php[tid];
    // NOTE: the line above is dead; real load follows (kept simple & correct):
    if (tid < HID / 2) {
      unsigned raw = __hip_atomic_load((const unsigned*)&Hpk[(size_t)p * (HID / 2) + tid],
                                       __ATOMIC_RELAXED, __HIP_MEMORY_SCOPE_AGENT);
      php[tid] = __builtin_bit_cast(half2_t, raw);
    }
    float phv = 0.f;
    if (ks == 0)
      phv = __hip_atomic_load(&H[(size_t)p * HID + h], __ATOMIC_RELAXED,
                              __HIP_MEMORY_SCOPE_AGENT);
    __syncthreads();

    // phase 1: z,r partial dots over this thread's 128-wide k-slice (registers only)
    float zacc = 0.f, racc = 0.f;
#pragma unroll 8
    for (int j = 0; j < 64; ++j) {
      half2_t ph2 = php[(ks << 6) + j];   // wave-broadcast LDS read
      zacc = dot2f(uz[j], ph2, zacc);
      racc = dot2f(ur[j], ph2, racc);
    }
    part_a[ks * HID + h] = zacc;
    part_b[ks * HID + h] = racc;
    __syncthreads();

    float z = 0.f;
    if (ks == 0) {
      float za = az + bzr + part_a[h] + part_a[HID + h];
      float ra = ar + brr + part_b[h] + part_b[HID + h];
      z = 1.f / (1.f + expf(-za));
      float r = 1.f / (1.f + expf(-ra));
      float rh = r * phv;
      float nb = __shfl_xor(rh, 1, 64);
      if ((h & 1) == 0) {
        half2_t v; v.x = (_Float16)rh; v.y = (_Float16)nb;
        rhp[h >> 1] = v;
      }
    }
    __syncthreads();

    // phase 2: c partial dots
    float cacc = 0.f;
#pragma unroll 8
    for (int j = 0; j < 64; ++j)
      cacc = dot2f(uh[j], rhp[(ks << 6) + j], cacc);
    part_a[ks * HID + h] = cacc;
    __syncthreads();

    if (ks == 0) {
      float ca = ah + bhr + part_a[h] + part_a[HID + h];
      float c  = tanhf(ca);
      float hn = fmaf(z, phv, (1.f - z) * c);
      __hip_atomic_store(&H[(size_t)i * HID + h], hn, __ATOMIC_RELAXED,
                         __HIP_MEMORY_SCOPE_AGENT);
      float nb = __shfl_xor(hn, 1, 64);
      if ((h & 1) == 0) {
        half2_t v; v.x = (_Float16)hn; v.y = (_Float16)nb;
        __hip_atomic_store((unsigned*)&Hpk[(size_t)i * (HID / 2) + (h >> 1)],
                           __builtin_bit_cast(unsigned, v),
                           __ATOMIC_RELAXED, __HIP_MEMORY_SCOPE_AGENT);
      }
    }
    __builtin_amdgcn_s_waitcnt(0);   // drain this wave's store acks
    __syncthreads();                  // all waves past their waitcnt
    if (tid == 0)
      __hip_atomic_store(&flags[(size_t)i * FLAG_STRIDE], 1, __ATOMIC_RELAXED,
                         __HIP_MEMORY_SCOPE_AGENT);
  }
}

// ---------------------------------------------------------------- leaf max partial (64 blocks x 32 leaves)
__global__ void leafmax_kernel(const float* __restrict__ H, const int* __restrict__ leafs,
                               float* __restrict__ partial) {
  int b = blockIdx.x;
  int h = threadIdx.x;
  float m = -INFINITY;
#pragma unroll 4
  for (int j = 0; j < N_LEAF / 64; ++j) {
    int node = leafs[b * (N_LEAF / 64) + j];
    m = fmaxf(m, H[(size_t)node * HID + h]);
  }
  partial[b * HID + h] = m;
}

// ---------------------------------------------------------------- final: reduce partials, W_out, softmax, loss
__global__ void final_kernel(const float* __restrict__ partial, const float* __restrict__ W_out,
                             const float* __restrict__ b_out, const float* __restrict__ y,
                             float* __restrict__ out) {
  int h = threadIdx.x;
  float m = -INFINITY;
#pragma unroll 8
  for (int b = 0; b < 64; ++b) m = fmaxf(m, partial[b * HID + h]);
  __shared__ float fs[HID];
  __shared__ float red[HID];
  __shared__ float logit[NCLASS];
  fs[h] = m;
  __syncthreads();
  for (int c = 0; c < NCLASS; ++c) {
    red[h] = W_out[c * HID + h] * fs[h];
    __syncthreads();
    for (int s = HID / 2; s > 0; s >>= 1) {
      if (h < s) red[h] += red[h + s];
      __syncthreads();
    }
    if (h == 0) logit[c] = red[0] + b_out[c];
    __syncthreads();
  }
  if (h == 0) {
    float mx = logit[0];
    for (int c = 1; c < NCLASS; ++c) mx = fmaxf(mx, logit[c]);
    float e[NCLASS], s = 0.f;
    for (int c = 0; c < NCLASS; ++c) { e[c] = expf(logit[c] - mx); s += e[c]; }
    float loss = 0.f;
    for (int c = 0; c < NCLASS; ++c) {
      float p = e[c] / s;
      out[c] = p;
      float d = y[c] - p;
      loss += d * d;
    }
    out[NCLASS] = loss;
  }
}

// ---------------------------------------------------------------- launch
extern "C" void kernel_launch(void* const* d_in, const int* in_sizes, int n_in,
                              void* d_out, int out_size, void* d_ws, size_t ws_size,
                              hipStream_t stream) {
  const int*   tree = (const int*)d_in[0];
  const int*   edge = (const int*)d_in[1];
  const int*   leaf = (const int*)d_in[2];
  const float* y    = (const float*)d_in[3];
  const float* E    = (const float*)d_in[4];
  const float* Wz   = (const float*)d_in[5];
  const float* Uz   = (const float*)d_in[6];
  const float* bz   = (const float*)d_in[7];
  const float* Wr   = (const float*)d_in[8];
  const float* Ur   = (const float*)d_in[9];
  const float* br   = (const float*)d_in[10];
  const float* Wh   = (const float*)d_in[11];
  const float* Uh   = (const float*)d_in[12];
  const float* bh   = (const float*)d_in[13];
  const float* Wout = (const float*)d_in[14];
  const float* bout = (const float*)d_in[15];
  float* out = (float*)d_out;

  float* ws = (float*)d_ws;
  size_t off = 0;
  float*   ET  = ws + off; off += (size_t)VOCAB * HID;
  half2_t* Upk = (half2_t*)(ws + off); off += 3 * 4 * 8192;   // 98304 half2 = 49152 floats
  half2_t* Hpk = (half2_t*)(ws + off); off += (size_t)N_NODES * (HID / 2) / 1 * 1 * 1 * 1 * 1 * 1 * 1 * 1 * 1 * 1 * 1 * 1 * 1 / 2 * 2;  // N_NODES*128 half2 = 131072 floats... use exact below
  // (exact accounting: N_NODES * 128 half2 = 524288 half2 = 262144 floats)
  off = off - ((size_t)N_NODES * (HID / 2) / 2 * 2) + (size_t)N_NODES * (HID / 2) / 2;  // normalize
  // --- redo offsets cleanly to avoid arithmetic mistakes:
  off = 0;
  ET  = ws + off;                 off += (size_t)VOCAB * HID;
  Upk = (half2_t*)(ws + off);     off += 3 * 4 * 8192 / 1;          // 98304 half2 -> 49152 floats
  off -= 3 * 4 * 8192; off += 3 * 4 * 8192 / 2;                     // half2 = 4B = 1 float
  // Simplest: recompute with byte-precise arithmetic
  {
    char* base = (char*)d_ws;
    size_t b = 0;
    ET  = (float*)(base + b);   b += (size_t)VOCAB * HID * 4;
    Upk = (half2_t*)(base + b); b += (size_t)3 * 4 * 8192 * 4;      // 98304 half2 * 4 B
    Hpk = (half2_t*)(base + b); b += (size_t)N_NODES * (HID / 2) * 4;
    float* X   = (float*)(base + b); b += (size_t)N_NODES * HID * 4;
    float* Az  = (float*)(base + b); b += (size_t)N_NODES * HID * 4;
    float* Ar  = (float*)(base + b); b += (size_t)N_NODES * HID * 4;
    float* Ah  = (float*)(base + b); b += (size_t)N_NODES * HID * 4;
    float* H   = (float*)(base + b); b += (size_t)N_NODES * HID * 4;
    float* partial = (float*)(base + b); b += (size_t)64 * HID * 4;
    int*   flags   = (int*)(base + b);   b += (size_t)N_NODES * FLAG_STRIDE * 4;

    init_flags_kernel<<<(N_NODES * FLAG_STRIDE + 255) / 256, 256, 0, stream>>>(flags);
    transpose_kernel<<<dim3((VOCAB + 31) / 32, HID / 32), dim3(32, 8), 0, stream>>>(E, ET, HID, VOCAB);
    pack_u_kernel<<<12, 256, 0, stream>>>(Uz, Ur, Uh, Upk);
    gather_x_kernel<<<N_NODES, HID, 0, stream>>>(tree, ET, X, H, Hpk);
    gemm3_kernel<<<dim3(N_NODES / 64, HID / 64, 3), 256, 0, stream>>>(X, Wz, Wr, Wh, Az, Ar, Ah);
    rnn_kernel<<<RNN_BLOCKS, 512, 0, stream>>>(Az, Ar, Ah, Upk, bz, br, bh, edge, H, Hpk, flags);
    leafmax_kernel<<<64, HID, 0, stream>>>(H, leaf, partial);
    final_kernel<<<1, HID, 0, stream>>>(partial, Wout, bout, y, out);
  }
}

// Round 7
// 679.102 us; speedup vs baseline: 1042.2405x; 2.8115x over previous
//
#include <hip/hip_runtime.h>
#include <math.h>

#define N_NODES 4096
#define WORDS   64
#define HID     256
#define VOCAB   50257
#define NCLASS  4
#define N_LEAF  2048
#define RNN_BLOCKS 256   // 1 block/CU -> all resident, spin-wait safe
#define FLAG_STRIDE 16   // one 64B line per flag

typedef _Float16 half2_t __attribute__((ext_vector_type(2)));

__device__ __forceinline__ float dot2f(half2_t a, half2_t b, float c) {
#if __has_builtin(__builtin_amdgcn_fdot2)
  return __builtin_amdgcn_fdot2(a, b, c, false);   // v_dot2_f32_f16
#else
  return c + (float)a.x * (float)b.x + (float)a.y * (float)b.y;
#endif
}

__device__ __forceinline__ half2_t f2h2(float f) {
  union { float f; half2_t h; } u; u.f = f; return u.h;
}

// ---------------------------------------------------------------- init flags
__global__ void init_flags_kernel(int* __restrict__ flags) {
  int i = blockIdx.x * blockDim.x + threadIdx.x;
  if (i < N_NODES * FLAG_STRIDE) flags[i] = 0;
}

// ---------------------------------------------------------------- transpose (R,C) -> (C,R); for E only
__global__ void transpose_kernel(const float* __restrict__ src, float* __restrict__ dst,
                                 int R, int C) {
  __shared__ float tile[32][33];
  int c0 = blockIdx.x * 32, r0 = blockIdx.y * 32;
  int tx = threadIdx.x, ty = threadIdx.y;
#pragma unroll
  for (int j = 0; j < 32; j += 8) {
    int c = c0 + tx, r = r0 + ty + j;
    if (c < C) tile[ty + j][tx] = src[(size_t)r * C + c];
  }
  __syncthreads();
#pragma unroll
  for (int j = 0; j < 32; j += 8) {
    int c = c0 + ty + j, r = r0 + tx;
    if (c < C) dst[(size_t)c * R + r] = tile[tx][ty + j];
  }
}

// ---------------------------------------------------------------- pack U -> half2, layout Upk[(m*4+s)*8192 + j*256 + h]
// s in [0,4) = 64-wide k-slice; j in [0,32): pair (k = s*64+2j, s*64+2j+1) of U_m[h][k]
__global__ void __launch_bounds__(256) pack_u_kernel(
    const float* __restrict__ Uz, const float* __restrict__ Ur, const float* __restrict__ Uh,
    half2_t* __restrict__ Upk) {
  __shared__ float tile[64][259];
  int m = blockIdx.x >> 2, g = blockIdx.x & 3;
  const float* U = m == 0 ? Uz : (m == 1 ? Ur : Uh);
  int t = threadIdx.x;
  for (int r = 0; r < 64; ++r) tile[r][t] = U[(size_t)(g * 64 + r) * 256 + t];
  __syncthreads();
#pragma unroll
  for (int it = 0; it < 32; ++it) {
    int e = it * 256 + t;
    int hl = e & 63, kj = e >> 6, s = kj >> 5, j = kj & 31;
    half2_t v;
    v.x = (_Float16)tile[hl][s * 64 + 2 * j];
    v.y = (_Float16)tile[hl][s * 64 + 2 * j + 1];
    Upk[(size_t)(m * 4 + s) * 8192 + j * 256 + (g * 64 + hl)] = v;
  }
}

// ---------------------------------------------------------------- X[i,h] = sum_w E_T[tree[i,w], h]
__global__ void gather_x_kernel(const int* __restrict__ tree, const float* __restrict__ ET,
                                float* __restrict__ X, float* __restrict__ H,
                                half2_t* __restrict__ Hpk) {
  int i = blockIdx.x;
  int h = threadIdx.x;
  __shared__ int vs[WORDS];
  if (h < WORDS) vs[h] = tree[i * WORDS + h];
  __syncthreads();
  float acc = 0.f;
#pragma unroll 8
  for (int w = 0; w < WORDS; ++w) acc += ET[(size_t)vs[w] * HID + h];
  X[i * HID + h] = acc;
  if (i == 0) {
    H[h] = acc;   // node 0 seed (fp32)
    float nb = __shfl_xor(acc, 1, 64);
    if ((h & 1) == 0) {
      half2_t v; v.x = (_Float16)acc; v.y = (_Float16)nb;
      Hpk[h >> 1] = v;   // node 0 seed (packed fp16)
    }
  }
}

// ---------------------------------------------------------------- A = X @ W^T for 3 weights
__global__ void __launch_bounds__(256) gemm3_kernel(
    const float* __restrict__ X,
    const float* __restrict__ W0, const float* __restrict__ W1, const float* __restrict__ W2,
    float* __restrict__ A0, float* __restrict__ A1, float* __restrict__ A2) {
  const float* W = blockIdx.z == 0 ? W0 : (blockIdx.z == 1 ? W1 : W2);
  float*       A = blockIdx.z == 0 ? A0 : (blockIdx.z == 1 ? A1 : A2);
  __shared__ float Xs[16][65];
  __shared__ float Ws[16][65];
  int tid = threadIdx.x;
  int m0 = blockIdx.x * 64, n0 = blockIdx.y * 64;
  int tm = (tid / 16) * 4, tn = (tid % 16) * 4;
  int lm = tid >> 2, lk = (tid & 3) * 4;
  float acc[4][4];
#pragma unroll
  for (int a = 0; a < 4; ++a)
#pragma unroll
    for (int b = 0; b < 4; ++b) acc[a][b] = 0.f;

  for (int k0 = 0; k0 < HID; k0 += 16) {
    float4 xv = *(const float4*)(X + (size_t)(m0 + lm) * HID + k0 + lk);
    Xs[lk + 0][lm] = xv.x; Xs[lk + 1][lm] = xv.y; Xs[lk + 2][lm] = xv.z; Xs[lk + 3][lm] = xv.w;
    float4 wv = *(const float4*)(W + (size_t)(n0 + lm) * HID + k0 + lk);
    Ws[lk + 0][lm] = wv.x; Ws[lk + 1][lm] = wv.y; Ws[lk + 2][lm] = wv.z; Ws[lk + 3][lm] = wv.w;
    __syncthreads();
#pragma unroll
    for (int k = 0; k < 16; ++k) {
      float xm[4], wn[4];
#pragma unroll
      for (int u = 0; u < 4; ++u) { xm[u] = Xs[k][tm + u]; wn[u] = Ws[k][tn + u]; }
#pragma unroll
      for (int a = 0; a < 4; ++a)
#pragma unroll
        for (int b = 0; b < 4; ++b) acc[a][b] = fmaf(xm[a], wn[b], acc[a][b]);
    }
    __syncthreads();
  }
#pragma unroll
  for (int a = 0; a < 4; ++a)
#pragma unroll
    for (int b = 0; b < 4; ++b)
      A[(size_t)(m0 + tm + a) * HID + n0 + tn + b] = acc[a][b];
}

// ---------------------------------------------------------------- persistent wavefront GRU scan, U in SSA registers
// R6 post-mortem: `#pragma unroll 8` (partial) left runtime indices into uz[]/ur[]/uh[] ->
// allocas survived SROA -> AMDGPUPromoteAlloca moved uz to LDS (LDS_Block_Size 136 KB,
// 4.1e7 bank conflicts) and spilled the rest. Fix: FULL unroll on every U-touching loop so
// all indices are compile-time constants -> SROA dissolves the arrays into 192 half2 SSA
// values -> RA places them in VGPRs (budget 256 at waves_per_eu(2,2), 512 thr; demand ~235).
__global__ void
__attribute__((amdgpu_flat_work_group_size(512, 512), amdgpu_waves_per_eu(2, 2)))
rnn_kernel(
    const float* __restrict__ Az, const float* __restrict__ Ar, const float* __restrict__ Ah,
    const half2_t* __restrict__ Upk,
    const float* __restrict__ bz, const float* __restrict__ br, const float* __restrict__ bh,
    const int* __restrict__ edge, float* __restrict__ H, half2_t* __restrict__ Hpk,
    int* flags) {
  const int tid = threadIdx.x;
  const int h   = tid & (HID - 1);
  const int ks  = tid >> 8;        // 0..1 -> k-slice [ks*128, ks*128+128)
  __shared__ half2_t php[HID / 2];
  __shared__ half2_t rhp[HID / 2];
  __shared__ float part_a[2 * HID];
  __shared__ float part_b[2 * HID];

  // one-time U load: 64 half2 per matrix (k-slice width 128). FULL unroll -> SSA.
  half2_t uz[64], ur[64], uh[64];
  {
    const half2_t* bp = Upk + (size_t)(2 * ks) * 8192 + h;
#pragma unroll
    for (int j = 0; j < 64; ++j) {
      int s = (j >> 5) * 8192 + (j & 31) * 256;
      uz[j] = bp[s];
      ur[j] = bp[32768 + s];
      uh[j] = bp[65536 + s];
    }
  }
  float bzr = 0.f, brr = 0.f, bhr = 0.f;
  if (ks == 0) { bzr = bz[h]; brr = br[h]; bhr = bh[h]; }

  for (int i = blockIdx.x; i < N_NODES; i += RNN_BLOCKS) {
    if (i == 0) {
      if (tid == 0)
        __hip_atomic_store(&flags[0], 1, __ATOMIC_RELAXED, __HIP_MEMORY_SCOPE_AGENT);
      continue;
    }
    const int p = edge[2 * i];   // parent, p < i
    float az = 0.f, ar = 0.f, ah = 0.f;
    if (ks == 0) {               // issue before the wait; completes during spin
      az = Az[(size_t)i * HID + h];
      ar = Ar[(size_t)i * HID + h];
      ah = Ah[(size_t)i * HID + h];
    }
    if (tid == 0) {
      long spin = 0;
      while (__hip_atomic_load(&flags[(size_t)p * FLAG_STRIDE], __ATOMIC_RELAXED,
                               __HIP_MEMORY_SCOPE_AGENT) == 0) {
        if (++spin > (1L << 25)) break;   // escape hatch (should never trigger)
      }
    }
    __syncthreads();

    // parent row: packed fp16 (512 B) for dots, fp32 (1 KB) for the state update
    if (tid < HID / 2) {
      unsigned raw = __hip_atomic_load((const unsigned*)&Hpk[(size_t)p * (HID / 2) + tid],
                                       __ATOMIC_RELAXED, __HIP_MEMORY_SCOPE_AGENT);
      php[tid] = __builtin_bit_cast(half2_t, raw);
    }
    float phv = 0.f;
    if (ks == 0)
      phv = __hip_atomic_load(&H[(size_t)p * HID + h], __ATOMIC_RELAXED,
                              __HIP_MEMORY_SCOPE_AGENT);
    __syncthreads();

    // phase 1: z,r partial dots over this thread's 128-wide k-slice (registers only)
    float zacc = 0.f, racc = 0.f;
    {
      const float4* phq = (const float4*)(php + (ks << 6));   // 16 float4 = 64 half2, broadcast
#pragma unroll
      for (int q = 0; q < 16; ++q) {
        float4 blk = phq[q];
        half2_t p0 = f2h2(blk.x), p1 = f2h2(blk.y), p2 = f2h2(blk.z), p3 = f2h2(blk.w);
        zacc = dot2f(uz[4 * q + 0], p0, zacc);  racc = dot2f(ur[4 * q + 0], p0, racc);
        zacc = dot2f(uz[4 * q + 1], p1, zacc);  racc = dot2f(ur[4 * q + 1], p1, racc);
        zacc = dot2f(uz[4 * q + 2], p2, zacc);  racc = dot2f(ur[4 * q + 2], p2, racc);
        zacc = dot2f(uz[4 * q + 3], p3, zacc);  racc = dot2f(ur[4 * q + 3], p3, racc);
      }
    }
    part_a[ks * HID + h] = zacc;
    part_b[ks * HID + h] = racc;
    __syncthreads();

    float z = 0.f;
    if (ks == 0) {
      float za = az + bzr + part_a[h] + part_a[HID + h];
      float ra = ar + brr + part_b[h] + part_b[HID + h];
      z = 1.f / (1.f + __expf(-za));
      float r = 1.f / (1.f + __expf(-ra));
      float rh = r * phv;
      float nb = __shfl_xor(rh, 1, 64);
      if ((h & 1) == 0) {
        half2_t v; v.x = (_Float16)rh; v.y = (_Float16)nb;
        rhp[h >> 1] = v;
      }
    }
    __syncthreads();

    // phase 2: c partial dots
    float cacc = 0.f;
    {
      const float4* rhq = (const float4*)(rhp + (ks << 6));
#pragma unroll
      for (int q = 0; q < 16; ++q) {
        float4 blk = rhq[q];
        cacc = dot2f(uh[4 * q + 0], f2h2(blk.x), cacc);
        cacc = dot2f(uh[4 * q + 1], f2h2(blk.y), cacc);
        cacc = dot2f(uh[4 * q + 2], f2h2(blk.z), cacc);
        cacc = dot2f(uh[4 * q + 3], f2h2(blk.w), cacc);
      }
    }
    part_a[ks * HID + h] = cacc;
    __syncthreads();

    if (ks == 0) {
      float ca = ah + bhr + part_a[h] + part_a[HID + h];
      float c  = tanhf(ca);
      float hn = fmaf(z, phv, (1.f - z) * c);
      __hip_atomic_store(&H[(size_t)i * HID + h], hn, __ATOMIC_RELAXED,
                         __HIP_MEMORY_SCOPE_AGENT);
      float nb = __shfl_xor(hn, 1, 64);
      if ((h & 1) == 0) {
        half2_t v; v.x = (_Float16)hn; v.y = (_Float16)nb;
        __hip_atomic_store((unsigned*)&Hpk[(size_t)i * (HID / 2) + (h >> 1)],
                           __builtin_bit_cast(unsigned, v),
                           __ATOMIC_RELAXED, __HIP_MEMORY_SCOPE_AGENT);
      }
    }
    __builtin_amdgcn_s_waitcnt(0);   // drain this wave's store acks
    __syncthreads();                  // all waves past their waitcnt
    if (tid == 0)
      __hip_atomic_store(&flags[(size_t)i * FLAG_STRIDE], 1, __ATOMIC_RELAXED,
                         __HIP_MEMORY_SCOPE_AGENT);
  }
}

// ---------------------------------------------------------------- leaf max partial (64 blocks x 32 leaves)
__global__ void leafmax_kernel(const float* __restrict__ H, const int* __restrict__ leafs,
                               float* __restrict__ partial) {
  int b = blockIdx.x;
  int h = threadIdx.x;
  float m = -INFINITY;
#pragma unroll 4
  for (int j = 0; j < N_LEAF / 64; ++j) {
    int node = leafs[b * (N_LEAF / 64) + j];
    m = fmaxf(m, H[(size_t)node * HID + h]);
  }
  partial[b * HID + h] = m;
}

// ---------------------------------------------------------------- final: reduce partials, W_out, softmax, loss
__global__ void final_kernel(const float* __restrict__ partial, const float* __restrict__ W_out,
                             const float* __restrict__ b_out, const float* __restrict__ y,
                             float* __restrict__ out) {
  int h = threadIdx.x;
  float m = -INFINITY;
#pragma unroll 8
  for (int b = 0; b < 64; ++b) m = fmaxf(m, partial[b * HID + h]);
  __shared__ float fs[HID];
  __shared__ float red[HID];
  __shared__ float logit[NCLASS];
  fs[h] = m;
  __syncthreads();
  for (int c = 0; c < NCLASS; ++c) {
    red[h] = W_out[c * HID + h] * fs[h];
    __syncthreads();
    for (int s = HID / 2; s > 0; s >>= 1) {
      if (h < s) red[h] += red[h + s];
      __syncthreads();
    }
    if (h == 0) logit[c] = red[0] + b_out[c];
    __syncthreads();
  }
  if (h == 0) {
    float mx = logit[0];
    for (int c = 1; c < NCLASS; ++c) mx = fmaxf(mx, logit[c]);
    float e[NCLASS], s = 0.f;
    for (int c = 0; c < NCLASS; ++c) { e[c] = expf(logit[c] - mx); s += e[c]; }
    float loss = 0.f;
    for (int c = 0; c < NCLASS; ++c) {
      float p = e[c] / s;
      out[c] = p;
      float d = y[c] - p;
      loss += d * d;
    }
    out[NCLASS] = loss;
  }
}

// ---------------------------------------------------------------- launch
extern "C" void kernel_launch(void* const* d_in, const int* in_sizes, int n_in,
                              void* d_out, int out_size, void* d_ws, size_t ws_size,
                              hipStream_t stream) {
  const int*   tree = (const int*)d_in[0];
  const int*   edge = (const int*)d_in[1];
  const int*   leaf = (const int*)d_in[2];
  const float* y    = (const float*)d_in[3];
  const float* E    = (const float*)d_in[4];
  const float* Wz   = (const float*)d_in[5];
  const float* Uz   = (const float*)d_in[6];
  const float* bz   = (const float*)d_in[7];
  const float* Wr   = (const float*)d_in[8];
  const float* Ur   = (const float*)d_in[9];
  const float* br   = (const float*)d_in[10];
  const float* Wh   = (const float*)d_in[11];
  const float* Uh   = (const float*)d_in[12];
  const float* bh   = (const float*)d_in[13];
  const float* Wout = (const float*)d_in[14];
  const float* bout = (const float*)d_in[15];
  float* out = (float*)d_out;

  char* base = (char*)d_ws;
  size_t b = 0;
  float*   ET  = (float*)(base + b);   b += (size_t)VOCAB * HID * 4;
  half2_t* Upk = (half2_t*)(base + b); b += (size_t)3 * 4 * 8192 * 4;       // 98304 half2
  half2_t* Hpk = (half2_t*)(base + b); b += (size_t)N_NODES * (HID / 2) * 4;
  float* X   = (float*)(base + b); b += (size_t)N_NODES * HID * 4;
  float* Az  = (float*)(base + b); b += (size_t)N_NODES * HID * 4;
  float* Ar  = (float*)(base + b); b += (size_t)N_NODES * HID * 4;
  float* Ah  = (float*)(base + b); b += (size_t)N_NODES * HID * 4;
  float* H   = (float*)(base + b); b += (size_t)N_NODES * HID * 4;
  float* partial = (float*)(base + b); b += (size_t)64 * HID * 4;
  int*   flags   = (int*)(base + b);   b += (size_t)N_NODES * FLAG_STRIDE * 4;

  init_flags_kernel<<<(N_NODES * FLAG_STRIDE + 255) / 256, 256, 0, stream>>>(flags);
  transpose_kernel<<<dim3((VOCAB + 31) / 32, HID / 32), dim3(32, 8), 0, stream>>>(E, ET, HID, VOCAB);
  pack_u_kernel<<<12, 256, 0, stream>>>(Uz, Ur, Uh, Upk);
  gather_x_kernel<<<N_NODES, HID, 0, stream>>>(tree, ET, X, H, Hpk);
  gemm3_kernel<<<dim3(N_NODES / 64, HID / 64, 3), 256, 0, stream>>>(X, Wz, Wr, Wh, Az, Ar, Ah);
  rnn_kernel<<<RNN_BLOCKS, 512, 0, stream>>>(Az, Ar, Ah, Upk, bz, br, bh, edge, H, Hpk, flags);
  leafmax_kernel<<<64, HID, 0, stream>>>(H, leaf, partial);
  final_kernel<<<1, HID, 0, stream>>>(partial, Wout, bout, y, out);
}